// Round 4
// baseline (129.172 us; speedup 1.0000x reference)
//
#include <hip/hip_runtime.h>
#include <hip/hip_bf16.h>

// ---------------------------------------------------------------------------
// EdgeConvNet — Round 4: swapped-operand MFMA + packed-fp32 conv build.
//
// C[g][n] = sum_f w1[g,f] * conv[n,f],  n = edge(2)·ch(8), via
// mfma_f32_16x16x32_bf16(A=w1, B=conv), K=64 in 2 MFMAs.
// C/D layout (HW-verified m89/m91): col = lane&15 = n, row = (lane>>4)*4+r = g.
//  -> fc2 (sum over g): 4-reg in-lane dot + xor16 + xor32   (2 DS ops)
//  -> fc3 (sum over ch): xor1 + xor2 + xor4                 (3 DS ops)
// R3's pass proves the A/B k-maps match: both fragments here use the same
// (grp, elem)->f assignment, so the hardware k-permutation cancels.
// Conv build uses float2 packed fma/max (v_pk_fma_f32) where available.
// Each wave: 16 edges = 8 tiles; indices preloaded, per-tile broadcast via
// shfl; next tile's 8 float4 gathers prefetched off 2 base addresses.
// ---------------------------------------------------------------------------

typedef short bf16x8 __attribute__((ext_vector_type(8)));
typedef float f32x4  __attribute__((ext_vector_type(4)));
typedef float f32x2  __attribute__((ext_vector_type(2)));

#if defined(__has_builtin)
#  if __has_builtin(__builtin_elementwise_fma) && __has_builtin(__builtin_elementwise_max)
#    define PK_MATH 1
#  endif
#endif

static __device__ __forceinline__ short f2bf(float f) {
    union { __hip_bfloat16 h; short s; } u;
    u.h = __float2bfloat16(f);
    return u.s;
}

__global__ __launch_bounds__(256) void edgeconv_mfma2(
    const float* __restrict__ features,   // (50000, 64) fp32
    const int*   __restrict__ edge_index, // (2, E) int32
    const float* __restrict__ conv_w,     // (8, 2)
    const float* __restrict__ conv_b,     // (8)
    const float* __restrict__ w1,         // (16, 64)
    const float* __restrict__ b1,         // (16)
    const float* __restrict__ w2,         // (16)
    const float* __restrict__ b2,         // (1)
    const float* __restrict__ w3,         // (8)
    const float* __restrict__ b3,         // (1)
    float*       __restrict__ out,        // (E)
    int nEdges)
{
    const int tid = threadIdx.x;
    const int l   = tid & 63;
    const int wid = tid >> 6;
    const int grp = l >> 4;        // k-slice group 0..3
    const int n   = l & 15;        // B col = edge·ch ; also A row = g
    const int ch  = l & 7;
    const int el  = (l >> 3) & 1;

    // --- A fragments: w1[g = n][f], f = grp*8+i (+32 for second MFMA)
    const float* w1r = w1 + n * 64 + grp * 8;
    bf16x8 aw0, aw1;
    #pragma unroll
    for (int i = 0; i < 8; ++i) {
        aw0[i] = f2bf(w1r[i]);
        aw1[i] = f2bf(w1r[32 + i]);
    }

    // --- per-lane params
    const float ca = conv_w[2 * ch];
    const float cc = conv_w[2 * ch + 1];
    const float cb = conv_b[ch];
    float b1r[4], w2r[4];                 // rows g = grp*4 + r held by this lane
    #pragma unroll
    for (int r = 0; r < 4; ++r) {
        b1r[r] = b1[grp * 4 + r];
        w2r[r] = w2[grp * 4 + r];
    }
    const float w3v = w3[ch];
    const float b2v = b2[0];
    const float b3v = b3[0];

    // --- this wave's 16 edges (lane n holds edge ebase+n's endpoints)
    const int ebase = (blockIdx.x * 4 + wid) * 16;
    const int ce    = min(ebase + n, nEdges - 1);
    const int vs    = edge_index[ce];
    const int vd    = edge_index[nEdges + ce];

    // loads: per lane 2 bases (src,dst), 4x float4 each at +0,+16,+128,+144 B
#define LOAD_TILE(T, X1, X2) do { \
    const int sn_ = __shfl(vs, 2 * (T) + el); \
    const int dn_ = __shfl(vd, 2 * (T) + el); \
    const float* p1_ = features + (size_t)sn_ * 64 + grp * 8; \
    const float* p2_ = features + (size_t)dn_ * 64 + grp * 8; \
    X1[0] = *(const f32x4*)(p1_);      X1[1] = *(const f32x4*)(p1_ + 4); \
    X1[2] = *(const f32x4*)(p1_ + 32); X1[3] = *(const f32x4*)(p1_ + 36); \
    X2[0] = *(const f32x4*)(p2_);      X2[1] = *(const f32x4*)(p2_ + 4); \
    X2[2] = *(const f32x4*)(p2_ + 32); X2[3] = *(const f32x4*)(p2_ + 36); \
} while (0)

    f32x4 x1v[4], x2v[4];
    LOAD_TILE(0, x1v, x2v);

#ifdef PK_MATH
    const f32x2 vca = {ca, ca}, vcc = {cc, cc}, vcb = {cb, cb};
    const f32x2 vz  = {0.f, 0.f};
#endif

    #pragma unroll
    for (int t = 0; t < 8; ++t) {
        f32x4 n1v[4], n2v[4];
        if (t < 7) LOAD_TILE(t + 1, n1v, n2v);

        // conv + relu + bf16 pack -> B fragments (elem i <-> f = grp*8+i)
        bf16x8 cf0, cf1;
        #pragma unroll
        for (int p = 0; p < 8; ++p) {            // pair p covers elems 2p,2p+1
            const int q  = p >> 1;               // which float4
            const int o  = (p & 1) * 2;          // offset inside float4
#ifdef PK_MATH
            f32x2 u = {x1v[q][o], x1v[q][o + 1]};
            f32x2 v = {x2v[q][o], x2v[q][o + 1]};
            f32x2 tt = __builtin_elementwise_fma(vca, u,
                        __builtin_elementwise_fma(vcc, v, vcb));
            tt = __builtin_elementwise_max(tt, vz);
            const short s0 = f2bf(tt[0]), s1 = f2bf(tt[1]);
#else
            const float t0 = fmaxf(fmaf(ca, x1v[q][o],     fmaf(cc, x2v[q][o],     cb)), 0.f);
            const float t1 = fmaxf(fmaf(ca, x1v[q][o + 1], fmaf(cc, x2v[q][o + 1], cb)), 0.f);
            const short s0 = f2bf(t0), s1 = f2bf(t1);
#endif
            if (p < 4) { cf0[2 * (p & 3)] = s0; cf0[2 * (p & 3) + 1] = s1; }
            else       { cf1[2 * (p & 3)] = s0; cf1[2 * (p & 3) + 1] = s1; }
        }

        // fc1 via MFMA: C[g][n], fp32 accum
        f32x4 acc = {0.f, 0.f, 0.f, 0.f};
        acc = __builtin_amdgcn_mfma_f32_16x16x32_bf16(aw0, cf0, acc, 0, 0, 0);
        acc = __builtin_amdgcn_mfma_f32_16x16x32_bf16(aw1, cf1, acc, 0, 0, 0);

        // fc2: in-lane dot over 4 g-rows, then combine the 4 grp groups
        float zp = 0.f;
        #pragma unroll
        for (int r = 0; r < 4; ++r) {
            const float h1 = fmaxf(acc[r] + b1r[r], 0.f);
            zp = fmaf(h1, w2r[r], zp);
        }
        zp += __shfl_xor(zp, 16);
        zp += __shfl_xor(zp, 32);

        // fc3: h2 = relu(z2 + b2); reduce over 8 channels in the el-octet
        const float h2 = fmaxf(zp + b2v, 0.f);
        float t3 = h2 * w3v;
        t3 += __shfl_xor(t3, 1);
        t3 += __shfl_xor(t3, 2);
        t3 += __shfl_xor(t3, 4);
        const float z  = t3 + b3v;
        const float sg = 1.0f / (1.0f + __expf(-z));

        if ((l & 55) == 0) {                  // lanes 0 (el=0) and 8 (el=1)
            const int e = ebase + 2 * t + (l >> 3);
            if (e < nEdges) out[e] = sg;
        }

        if (t < 7) {
            #pragma unroll
            for (int i = 0; i < 4; ++i) { x1v[i] = n1v[i]; x2v[i] = n2v[i]; }
        }
    }
#undef LOAD_TILE
}

extern "C" void kernel_launch(void* const* d_in, const int* in_sizes, int n_in,
                              void* d_out, int out_size, void* d_ws, size_t ws_size,
                              hipStream_t stream) {
    // 0:x 1:features 2:edge_index 3:conv_w 4:conv_b 5:w1 6:b1 7:w2 8:b2 9:w3 10:b3
    const float* features = (const float*)d_in[1];
    const int*   edge_idx = (const int*)d_in[2];
    const float* conv_w   = (const float*)d_in[3];
    const float* conv_b   = (const float*)d_in[4];
    const float* w1       = (const float*)d_in[5];
    const float* b1       = (const float*)d_in[6];
    const float* w2       = (const float*)d_in[7];
    const float* b2       = (const float*)d_in[8];
    const float* w3       = (const float*)d_in[9];
    const float* b3       = (const float*)d_in[10];
    float*       out      = (float*)d_out;

    const int nEdges = in_sizes[2] / 2;          // (2, E)
    // each block: 4 waves x 16 edges = 64 edges
    const dim3 grid((nEdges + 63) / 64);
    const dim3 block(256);
    edgeconv_mfma2<<<grid, block, 0, stream>>>(features, edge_idx,
                                               conv_w, conv_b, w1, b1, w2, b2, w3, b3,
                                               out, nEdges);
}

// Round 5
// 96.054 us; speedup vs baseline: 1.3448x; 1.3448x over previous
//
#include <hip/hip_runtime.h>
#include <hip/hip_bf16.h>

// ---------------------------------------------------------------------------
// EdgeConvNet — Round 5: f16 feature pre-pass + packed-f16 conv + f16 MFMA.
//
// Pre-pass: features fp32 (12.8 MB) -> f16 (6.4 MB) in d_ws. Halves gather
// bytes AND the L2 working set (6.4 MB vs 4 MB/XCD -> much higher hit rate).
//
// Main kernel (per 2-edge tile, per wave):
//   conv: native v_pk_fma_f16 / v_pk_max_f16 on packed f16 pairs, output
//         pairs ARE the mfma B-fragment (no unpack, no cvt, no repack).
//   fc1:  C[g][n] = mfma_f32_16x16x32_f16(A=w1(f16), B=conv), K=64 in 2.
//         C/D layout (HW-verified, dtype-indep): col=lane&15=n, row=grp*4+r=g.
//   fc2:  in-lane 4-reg dot + xor16 + xor32.   fc3: xor1+xor2+xor4.
//   Prefetch depth 2 (8 loads in flight per wave) to widen MLP.
// Fallback (ws too small): round-4 bf16 kernel (proven).
// ---------------------------------------------------------------------------

typedef _Float16 f16x8 __attribute__((ext_vector_type(8)));
typedef _Float16 f16x4 __attribute__((ext_vector_type(4)));
typedef _Float16 f16x2 __attribute__((ext_vector_type(2)));
typedef short    bf16x8 __attribute__((ext_vector_type(8)));
typedef float    f32x4 __attribute__((ext_vector_type(4)));
typedef float    f32x2 __attribute__((ext_vector_type(2)));

struct Chunk { f16x2 p[4]; };   // 8 f16 = 16 B, viewed as 4 packed pairs

static __device__ __forceinline__ short f2bf(float f) {
    union { __hip_bfloat16 h; short s; } u;
    u.h = __float2bfloat16(f);
    return u.s;
}

// ---------------------------- pre-pass ------------------------------------
__global__ __launch_bounds__(256) void feat_to_f16(const float* __restrict__ in,
                                                   _Float16* __restrict__ out,
                                                   int n4) {
    int i = blockIdx.x * blockDim.x + threadIdx.x;
    const int stride = gridDim.x * blockDim.x;
    for (; i < n4; i += stride) {
        const f32x4 v = ((const f32x4*)in)[i];
        ((f16x4*)out)[i] = __builtin_convertvector(v, f16x4);
    }
}

// ---------------------------- main (f16) -----------------------------------
__global__ __launch_bounds__(256) void edgeconv_f16(
    const _Float16* __restrict__ feat16,     // (50000, 64) f16 (in d_ws)
    const int*      __restrict__ edge_index, // (2, E) int32
    const float* __restrict__ conv_w, const float* __restrict__ conv_b,
    const float* __restrict__ w1,     const float* __restrict__ b1,
    const float* __restrict__ w2,     const float* __restrict__ b2,
    const float* __restrict__ w3,     const float* __restrict__ b3,
    float* __restrict__ out, int nEdges)
{
    const int tid = threadIdx.x;
    const int l   = tid & 63;
    const int wid = tid >> 6;
    const int grp = l >> 4;        // k-slice group 0..3
    const int n   = l & 15;        // A row = g ; B col = edge·ch
    const int ch  = l & 7;
    const int el  = (l >> 3) & 1;

    // A fragments: w1[g=n][f], f = grp*8+i (+32 for 2nd MFMA), in f16
    const float* w1r = w1 + n * 64 + grp * 8;
    f16x8 aw0, aw1;
    #pragma unroll
    for (int i = 0; i < 8; ++i) {
        aw0[i] = (_Float16)w1r[i];
        aw1[i] = (_Float16)w1r[32 + i];
    }

    // conv params as packed-f16 splats
    const _Float16 cah = (_Float16)conv_w[2 * ch];
    const _Float16 cch = (_Float16)conv_w[2 * ch + 1];
    const _Float16 cbh = (_Float16)conv_b[ch];
    const f16x2 vca = {cah, cah}, vcc = {cch, cch}, vcb = {cbh, cbh};
    const f16x2 vzero = {(_Float16)0.f, (_Float16)0.f};

    float b1r[4], w2r[4];
    #pragma unroll
    for (int r = 0; r < 4; ++r) {
        b1r[r] = b1[grp * 4 + r];
        w2r[r] = w2[grp * 4 + r];
    }
    const float w3v = w3[ch];
    const float b2v = b2[0];
    const float b3v = b3[0];

    // this wave's 16 edges (lane n holds edge ebase+n's endpoints)
    const int ebase = (blockIdx.x * 4 + wid) * 16;
    const int ce    = min(ebase + n, nEdges - 1);
    const int vs    = edge_index[ce];
    const int vd    = edge_index[nEdges + ce];

    // per tile: src row chunks (L: f=grp*8.., H: +32) and dst likewise
#define LOAD_TILE(T, SL, SH, DL, DH) do { \
    const int sn_ = __shfl(vs, 2 * (T) + el); \
    const int dn_ = __shfl(vd, 2 * (T) + el); \
    const _Float16* p1_ = feat16 + (size_t)sn_ * 64 + grp * 8; \
    const _Float16* p2_ = feat16 + (size_t)dn_ * 64 + grp * 8; \
    SL = *(const Chunk*)(p1_);      SH = *(const Chunk*)(p1_ + 32); \
    DL = *(const Chunk*)(p2_);      DH = *(const Chunk*)(p2_ + 32); \
} while (0)

    Chunk sL[2], sH[2], dL[2], dH[2];
    LOAD_TILE(0, sL[0], sH[0], dL[0], dH[0]);
    LOAD_TILE(1, sL[1], sH[1], dL[1], dH[1]);

    #pragma unroll
    for (int t = 0; t < 8; ++t) {
        const int b = t & 1;

        // conv + relu directly in packed f16 -> B fragments
        union { f16x2 p[4]; f16x8 v; } c0, c1;
        #pragma unroll
        for (int i = 0; i < 4; ++i) {
            f16x2 tL = __builtin_elementwise_fma(vca, sL[b].p[i],
                        __builtin_elementwise_fma(vcc, dL[b].p[i], vcb));
            c0.p[i] = __builtin_elementwise_max(tL, vzero);
            f16x2 tH = __builtin_elementwise_fma(vca, sH[b].p[i],
                        __builtin_elementwise_fma(vcc, dH[b].p[i], vcb));
            c1.p[i] = __builtin_elementwise_max(tH, vzero);
        }

        // prefetch tile t+2 into the buffer just consumed
        if (t < 6) LOAD_TILE(t + 2, sL[b], sH[b], dL[b], dH[b]);

        // fc1 via MFMA: C[g][n], fp32 accum
        f32x4 acc = {0.f, 0.f, 0.f, 0.f};
        acc = __builtin_amdgcn_mfma_f32_16x16x32_f16(aw0, c0.v, acc, 0, 0, 0);
        acc = __builtin_amdgcn_mfma_f32_16x16x32_f16(aw1, c1.v, acc, 0, 0, 0);

        // fc2: in-lane dot over 4 g-rows, combine the 4 grp groups
        float zp = 0.f;
        #pragma unroll
        for (int r = 0; r < 4; ++r) {
            const float h1 = fmaxf(acc[r] + b1r[r], 0.f);
            zp = fmaf(h1, w2r[r], zp);
        }
        zp += __shfl_xor(zp, 16);
        zp += __shfl_xor(zp, 32);

        // fc3: reduce over 8 channels in the el-octet
        const float h2 = fmaxf(zp + b2v, 0.f);
        float t3 = h2 * w3v;
        t3 += __shfl_xor(t3, 1);
        t3 += __shfl_xor(t3, 2);
        t3 += __shfl_xor(t3, 4);
        const float z  = t3 + b3v;
        const float sg = 1.0f / (1.0f + __expf(-z));

        if ((l & 55) == 0) {                  // lanes 0 (el=0) and 8 (el=1)
            const int e = ebase + 2 * t + (l >> 3);
            if (e < nEdges) out[e] = sg;
        }
    }
#undef LOAD_TILE
}

// ------------------- fallback: round-4 bf16 kernel (proven) ----------------
__global__ __launch_bounds__(256) void edgeconv_mfma2(
    const float* __restrict__ features, const int* __restrict__ edge_index,
    const float* __restrict__ conv_w, const float* __restrict__ conv_b,
    const float* __restrict__ w1, const float* __restrict__ b1,
    const float* __restrict__ w2, const float* __restrict__ b2,
    const float* __restrict__ w3, const float* __restrict__ b3,
    float* __restrict__ out, int nEdges)
{
    const int tid = threadIdx.x;
    const int l   = tid & 63;
    const int wid = tid >> 6;
    const int grp = l >> 4;
    const int n   = l & 15;
    const int ch  = l & 7;
    const int el  = (l >> 3) & 1;

    const float* w1r = w1 + n * 64 + grp * 8;
    bf16x8 aw0, aw1;
    #pragma unroll
    for (int i = 0; i < 8; ++i) {
        aw0[i] = f2bf(w1r[i]);
        aw1[i] = f2bf(w1r[32 + i]);
    }
    const float ca = conv_w[2 * ch];
    const float cc = conv_w[2 * ch + 1];
    const float cb = conv_b[ch];
    float b1r[4], w2r[4];
    #pragma unroll
    for (int r = 0; r < 4; ++r) { b1r[r] = b1[grp * 4 + r]; w2r[r] = w2[grp * 4 + r]; }
    const float w3v = w3[ch];
    const float b2v = b2[0];
    const float b3v = b3[0];

    const int ebase = (blockIdx.x * 4 + wid) * 16;
    const int ce    = min(ebase + n, nEdges - 1);
    const int vs    = edge_index[ce];
    const int vd    = edge_index[nEdges + ce];

#define LOAD_TILE4(T, X1, X2) do { \
    const int sn_ = __shfl(vs, 2 * (T) + el); \
    const int dn_ = __shfl(vd, 2 * (T) + el); \
    const float* p1_ = features + (size_t)sn_ * 64 + grp * 8; \
    const float* p2_ = features + (size_t)dn_ * 64 + grp * 8; \
    X1[0] = *(const f32x4*)(p1_);      X1[1] = *(const f32x4*)(p1_ + 4); \
    X1[2] = *(const f32x4*)(p1_ + 32); X1[3] = *(const f32x4*)(p1_ + 36); \
    X2[0] = *(const f32x4*)(p2_);      X2[1] = *(const f32x4*)(p2_ + 4); \
    X2[2] = *(const f32x4*)(p2_ + 32); X2[3] = *(const f32x4*)(p2_ + 36); \
} while (0)

    f32x4 x1v[4], x2v[4];
    LOAD_TILE4(0, x1v, x2v);
    const f32x2 vca = {ca, ca}, vcc = {cc, cc}, vcb = {cb, cb};
    const f32x2 vz  = {0.f, 0.f};

    #pragma unroll
    for (int t = 0; t < 8; ++t) {
        f32x4 n1v[4], n2v[4];
        if (t < 7) LOAD_TILE4(t + 1, n1v, n2v);
        bf16x8 cf0, cf1;
        #pragma unroll
        for (int p = 0; p < 8; ++p) {
            const int q = p >> 1;
            const int o = (p & 1) * 2;
            f32x2 u = {x1v[q][o], x1v[q][o + 1]};
            f32x2 v = {x2v[q][o], x2v[q][o + 1]};
            f32x2 tt = __builtin_elementwise_fma(vca, u,
                        __builtin_elementwise_fma(vcc, v, vcb));
            tt = __builtin_elementwise_max(tt, vz);
            const short s0 = f2bf(tt[0]), s1 = f2bf(tt[1]);
            if (p < 4) { cf0[2 * (p & 3)] = s0; cf0[2 * (p & 3) + 1] = s1; }
            else       { cf1[2 * (p & 3)] = s0; cf1[2 * (p & 3) + 1] = s1; }
        }
        f32x4 acc = {0.f, 0.f, 0.f, 0.f};
        acc = __builtin_amdgcn_mfma_f32_16x16x32_bf16(aw0, cf0, acc, 0, 0, 0);
        acc = __builtin_amdgcn_mfma_f32_16x16x32_bf16(aw1, cf1, acc, 0, 0, 0);
        float zp = 0.f;
        #pragma unroll
        for (int r = 0; r < 4; ++r) {
            const float h1 = fmaxf(acc[r] + b1r[r], 0.f);
            zp = fmaf(h1, w2r[r], zp);
        }
        zp += __shfl_xor(zp, 16);
        zp += __shfl_xor(zp, 32);
        const float h2 = fmaxf(zp + b2v, 0.f);
        float t3 = h2 * w3v;
        t3 += __shfl_xor(t3, 1);
        t3 += __shfl_xor(t3, 2);
        t3 += __shfl_xor(t3, 4);
        const float z  = t3 + b3v;
        const float sg = 1.0f / (1.0f + __expf(-z));
        if ((l & 55) == 0) {
            const int e = ebase + 2 * t + (l >> 3);
            if (e < nEdges) out[e] = sg;
        }
        if (t < 7) {
            #pragma unroll
            for (int i = 0; i < 4; ++i) { x1v[i] = n1v[i]; x2v[i] = n2v[i]; }
        }
    }
#undef LOAD_TILE4
}

extern "C" void kernel_launch(void* const* d_in, const int* in_sizes, int n_in,
                              void* d_out, int out_size, void* d_ws, size_t ws_size,
                              hipStream_t stream) {
    // 0:x 1:features 2:edge_index 3:conv_w 4:conv_b 5:w1 6:b1 7:w2 8:b2 9:w3 10:b3
    const float* features = (const float*)d_in[1];
    const int*   edge_idx = (const int*)d_in[2];
    const float* conv_w   = (const float*)d_in[3];
    const float* conv_b   = (const float*)d_in[4];
    const float* w1       = (const float*)d_in[5];
    const float* b1       = (const float*)d_in[6];
    const float* w2       = (const float*)d_in[7];
    const float* b2       = (const float*)d_in[8];
    const float* w3       = (const float*)d_in[9];
    const float* b3       = (const float*)d_in[10];
    float*       out      = (float*)d_out;

    const int nEdges = in_sizes[2] / 2;          // (2, E)
    const int nFeat  = in_sizes[1];              // 50000*64
    const dim3 grid((nEdges + 63) / 64);         // 4 waves x 16 edges / block
    const dim3 block(256);

    const size_t need = (size_t)nFeat * sizeof(_Float16);
    if (ws_size >= need) {
        _Float16* feat16 = (_Float16*)d_ws;
        feat_to_f16<<<2048, 256, 0, stream>>>(features, feat16, nFeat / 4);
        edgeconv_f16<<<grid, block, 0, stream>>>(feat16, edge_idx,
                                                 conv_w, conv_b, w1, b1, w2, b2, w3, b3,
                                                 out, nEdges);
    } else {
        edgeconv_mfma2<<<grid, block, 0, stream>>>(features, edge_idx,
                                                   conv_w, conv_b, w1, b1, w2, b2, w3, b3,
                                                   out, nEdges);
    }
}